// Round 5
// baseline (1004.692 us; speedup 1.0000x reference)
//
#include <hip/hip_runtime.h>
#include <hip/hip_bf16.h>
#include <cstdint>
#include <cstddef>

typedef unsigned short u16;
typedef short bf16x8 __attribute__((ext_vector_type(8)));
typedef float f32x4 __attribute__((ext_vector_type(4)));

#define HH 3072
#define LL 2048
#define NHEAD 24
#define HD 128
#define MLP 12288
#define N1 21504   // 3H + M
#define QKVW 9216  // 3H
#define K2 15360   // H + M

__device__ __forceinline__ float b2f(u16 u) {
  union { float f; uint32_t i; } v; v.i = ((uint32_t)u) << 16; return v.f;
}
__device__ __forceinline__ u16 f2b(float f) {
  union { float f; uint32_t i; } v; v.f = f;
  return (u16)((v.i + 0x7fffu + ((v.i >> 16) & 1u)) >> 16);
}
__device__ __forceinline__ void gload16(const u16* g, u16* l) {
  __builtin_amdgcn_global_load_lds(
      (const __attribute__((address_space(1))) void*)g,
      (__attribute__((address_space(3))) void*)l, 16, 0, 0);
}
// bijective XCD-chunked swizzle (m204)
__device__ __forceinline__ int xcd_swz(int bid, int nwg) {
  int q = nwg >> 3, r = nwg & 7;
  int xcd = bid & 7, idx = bid >> 3;
  int base = (xcd < r) ? xcd * (q + 1) : r * (q + 1) + (xcd - r) * q;
  return base + idx;
}

// ---------------- small prep kernels ----------------

__global__ void k_silu(const float* __restrict__ vec, float* __restrict__ sv, int n) {
  int i = blockIdx.x * blockDim.x + threadIdx.x;
  if (i < n) { float v = vec[i]; sv[i] = v / (1.f + expf(-v)); }
}

__global__ void k_f2b8(const float* __restrict__ in, u16* __restrict__ out, size_t n) {
  size_t i = ((size_t)blockIdx.x * blockDim.x + threadIdx.x) * 8;
  if (i >= n) return;
  float4 a = *(const float4*)(in + i);
  float4 b = *(const float4*)(in + i + 4);
  bf16x8 o;
  o[0] = (short)f2b(a.x); o[1] = (short)f2b(a.y); o[2] = (short)f2b(a.z); o[3] = (short)f2b(a.w);
  o[4] = (short)f2b(b.x); o[5] = (short)f2b(b.y); o[6] = (short)f2b(b.z); o[7] = (short)f2b(b.w);
  *(bf16x8*)(out + i) = o;
}

__global__ __launch_bounds__(256) void k_modlin(
    const float* __restrict__ sv, const float* __restrict__ mw,
    const float* __restrict__ mb, float* __restrict__ mod) {
  int wave = (blockIdx.x * 256 + threadIdx.x) >> 6;
  int lane = threadIdx.x & 63;
  if (wave >= QKVW) return;
  const float* row = mw + (size_t)wave * HH;
  float s = 0.f;
#pragma unroll
  for (int i = 0; i < 12; i++) {
    int idx = i * 256 + lane * 4;
    float4 a = *(const float4*)(row + idx);
    float4 b = *(const float4*)(sv + idx);
    s += a.x * b.x + a.y * b.y + a.z * b.z + a.w * b.w;
  }
#pragma unroll
  for (int m = 32; m; m >>= 1) s += __shfl_xor(s, m);
  if (lane == 0) mod[wave] = s + mb[wave];
}

__global__ __launch_bounds__(256) void k_ln(
    const float* __restrict__ x, const float* __restrict__ mod, u16* __restrict__ xmod) {
  int row = blockIdx.x, t = threadIdx.x, lane = t & 63, w = t >> 6;
  const float* xr = x + (size_t)row * HH;
  float4 v[3];
  float s1 = 0.f, s2 = 0.f;
#pragma unroll
  for (int i = 0; i < 3; i++) {
    v[i] = *(const float4*)(xr + t * 4 + i * 1024);
    s1 += v[i].x + v[i].y + v[i].z + v[i].w;
    s2 += v[i].x * v[i].x + v[i].y * v[i].y + v[i].z * v[i].z + v[i].w * v[i].w;
  }
#pragma unroll
  for (int m = 32; m; m >>= 1) { s1 += __shfl_xor(s1, m); s2 += __shfl_xor(s2, m); }
  __shared__ float red[8];
  if (lane == 0) { red[w] = s1; red[4 + w] = s2; }
  __syncthreads();
  s1 = red[0] + red[1] + red[2] + red[3];
  s2 = red[4] + red[5] + red[6] + red[7];
  float mu = s1 * (1.f / HH);
  float var = s2 * (1.f / HH) - mu * mu;
  float rstd = rsqrtf(var + 1e-6f);
#pragma unroll
  for (int i = 0; i < 3; i++) {
    int nb = t * 4 + i * 1024;
    ushort4 o;
    o.x = f2b((v[i].x - mu) * rstd * (1.f + mod[HH + nb + 0]) + mod[nb + 0]);
    o.y = f2b((v[i].y - mu) * rstd * (1.f + mod[HH + nb + 1]) + mod[nb + 1]);
    o.z = f2b((v[i].z - mu) * rstd * (1.f + mod[HH + nb + 2]) + mod[nb + 2]);
    o.w = f2b((v[i].w - mu) * rstd * (1.f + mod[HH + nb + 3]) + mod[nb + 3]);
    *(ushort4*)(xmod + (size_t)row * HH + nb) = o;
  }
}

// ================= 256x256 8-phase GEMM (m201 template, plain HIP) =================
// (unchanged from round 4 — verified passing)

#define MFMA_Q(AF, MB) do {                                                                   \
  _Pragma("unroll")                                                                           \
  for (int nf_ = 0; nf_ < 4; ++nf_) {                                                         \
    acc[MB][nf_]     = __builtin_amdgcn_mfma_f32_16x16x32_bf16(AF[0][0], bfr[nf_][0], acc[MB][nf_],     0,0,0); \
    acc[MB][nf_]     = __builtin_amdgcn_mfma_f32_16x16x32_bf16(AF[0][1], bfr[nf_][1], acc[MB][nf_],     0,0,0); \
    acc[(MB)+1][nf_] = __builtin_amdgcn_mfma_f32_16x16x32_bf16(AF[1][0], bfr[nf_][0], acc[(MB)+1][nf_], 0,0,0); \
    acc[(MB)+1][nf_] = __builtin_amdgcn_mfma_f32_16x16x32_bf16(AF[1][1], bfr[nf_][1], acc[(MB)+1][nf_], 0,0,0); \
  } } while (0)

#define STA(tt, half) do {                                                                    \
  const u16* g_ = gA + (size_t)((half) * 128) * kstride + (size_t)(tt) * 64;                  \
  int l_ = lA + ((tt) & 1) * 16384 + (half) * 8192;                                           \
  gload16(g_, lds + l_); gload16(g_ + 64 * kstride, lds + l_ + 4096); } while (0)

#define STB(tt, half) do {                                                                    \
  const u16* g_ = gB + (size_t)((half) * 128) * kstride + (size_t)(tt) * 64;                  \
  int l_ = lB + ((tt) & 1) * 16384 + (half) * 8192;                                           \
  gload16(g_, lds + l_); gload16(g_ + 64 * kstride, lds + l_ + 4096); } while (0)

template <int MODE>
__global__ __launch_bounds__(512, 2) void k_gemm256(
    const u16* __restrict__ Aall, const u16* __restrict__ Ball,
    const float* __restrict__ bias, u16* __restrict__ oq,
    u16* __restrict__ oh2, float* __restrict__ oparts) {
  __shared__ __align__(16) u16 lds[65536];   // 131072 bytes: A [0,32768), B [32768,65536)
  const int wgid = xcd_swz(blockIdx.x, gridDim.x);
  int m0, n0, NT; size_t kstride;
  const u16 *A, *Bw;
  if (MODE == 0) {
    m0 = (wgid & 7) * 256; n0 = (wgid >> 3) * 256; NT = 48; kstride = 3072;
    A = Aall + (size_t)m0 * kstride; Bw = Ball + (size_t)n0 * kstride;
  } else {
    m0 = (wgid & 7) * 256; int ks = (wgid >> 3) & 1; n0 = (wgid >> 4) * 256; NT = 120; kstride = 15360;
    A = Aall + (size_t)m0 * kstride + (size_t)ks * 7680;
    Bw = Ball + (size_t)n0 * kstride + (size_t)ks * 7680;
    oparts += (size_t)ks * 2048 * 3072;
  }
  const int tid = threadIdx.x, lane = tid & 63, w = tid >> 6;
  const int wr = w >> 2, wc = w & 3;
  const int fr = lane & 15, gq = lane >> 4;
  const int apb = ((gq ^ (fr & 3)) | (fr & 4)) * 8;
  const int aoff = wr * 8192 + fr * 64 + apb;
  const int boff = 32768 + (wc >> 1) * 8192 + ((wc & 1) * 64 + fr) * 64 + apb;
  const int srow = w * 8 + (lane >> 3);
  const int scol = ((lane & 7) ^ (lane >> 3)) * 8;
  const u16* gA = A + (size_t)srow * kstride + scol;
  const u16* gB = Bw + (size_t)srow * kstride + scol;
  const int lA = w * 512 + lane * 8;
  const int lB = 32768 + w * 512 + lane * 8;

  f32x4 acc[8][4] = {};
  STB(0, 0); STB(0, 1); STA(0, 0); STA(0, 1);
  STB(1, 0); STB(1, 1); STA(1, 0);
  asm volatile("s_waitcnt vmcnt(6)" ::: "memory");
  __builtin_amdgcn_s_barrier();

  for (int t = 0; t < NT; ++t) {
    const int p16 = (t & 1) * 16384;
    bf16x8 bfr[4][2], aA[2][2], aB[2][2], aC[2][2], aD[2][2];
#pragma unroll
    for (int nf = 0; nf < 4; ++nf) {
      int ix = boff + p16 + nf * 1024;
      bfr[nf][0] = *(const bf16x8*)(lds + ix);
      bfr[nf][1] = *(const bf16x8*)(lds + (ix ^ 32));
    }
#pragma unroll
    for (int mf = 0; mf < 2; ++mf) {
      int ix = aoff + p16 + mf * 1024;
      aA[mf][0] = *(const bf16x8*)(lds + ix);
      aA[mf][1] = *(const bf16x8*)(lds + (ix ^ 32));
    }
    if (t + 1 < NT) STA(t + 1, 1);
    __builtin_amdgcn_s_barrier();
    asm volatile("s_waitcnt lgkmcnt(0)" ::: "memory");
    __builtin_amdgcn_s_setprio(1);
    MFMA_Q(aA, 0);
    __builtin_amdgcn_s_setprio(0);
    __builtin_amdgcn_s_barrier();
#pragma unroll
    for (int mf = 0; mf < 2; ++mf) {
      int ix = aoff + p16 + (mf + 2) * 1024;
      aB[mf][0] = *(const bf16x8*)(lds + ix);
      aB[mf][1] = *(const bf16x8*)(lds + (ix ^ 32));
    }
#pragma unroll
    for (int mf = 0; mf < 2; ++mf) {
      int ix = aoff + p16 + (mf + 4) * 1024;
      aC[mf][0] = *(const bf16x8*)(lds + ix);
      aC[mf][1] = *(const bf16x8*)(lds + (ix ^ 32));
    }
    if (t + 2 < NT) STB(t + 2, 0);
    __builtin_amdgcn_s_barrier();
    asm volatile("s_waitcnt lgkmcnt(0)" ::: "memory");
    __builtin_amdgcn_s_setprio(1);
    MFMA_Q(aB, 2);
    __builtin_amdgcn_s_setprio(0);
    __builtin_amdgcn_s_barrier();
#pragma unroll
    for (int mf = 0; mf < 2; ++mf) {
      int ix = aoff + p16 + (mf + 6) * 1024;
      aD[mf][0] = *(const bf16x8*)(lds + ix);
      aD[mf][1] = *(const bf16x8*)(lds + (ix ^ 32));
    }
    if (t + 2 < NT) STB(t + 2, 1);
    __builtin_amdgcn_s_barrier();
    asm volatile("s_waitcnt lgkmcnt(0)" ::: "memory");
    __builtin_amdgcn_s_setprio(1);
    MFMA_Q(aC, 4);
    __builtin_amdgcn_s_setprio(0);
    __builtin_amdgcn_s_barrier();
    if (t + 2 < NT) STA(t + 2, 0);
    __builtin_amdgcn_s_barrier();
    __builtin_amdgcn_s_setprio(1);
    MFMA_Q(aD, 6);
    __builtin_amdgcn_s_setprio(0);
    if (t + 2 < NT)      asm volatile("s_waitcnt vmcnt(6)" ::: "memory");
    else if (t + 1 < NT) asm volatile("s_waitcnt vmcnt(0)" ::: "memory");
    __builtin_amdgcn_s_barrier();
  }

#pragma unroll
  for (int mf = 0; mf < 8; ++mf) {
    const int r0 = m0 + wr * 128 + mf * 16 + gq * 4;
#pragma unroll
    for (int nf = 0; nf < 4; ++nf) {
      const int n = n0 + wc * 64 + nf * 16 + fr;
      if (MODE == 0) {
        const float bv = bias[n];
        if (n0 >= QKVW) {
#pragma unroll
          for (int j = 0; j < 4; ++j) {
            float u = acc[mf][nf][j] + bv;
            float c = 0.7978845608028654f * (u + 0.044715f * u * u * u);
            float g = 0.5f * u * (1.f + tanhf(c));
            oh2[(size_t)(r0 + j) * K2 + HH + (n - QKVW)] = f2b(g);
          }
        } else {
#pragma unroll
          for (int j = 0; j < 4; ++j)
            oq[(size_t)(r0 + j) * QKVW + n] = f2b(acc[mf][nf][j] + bv);
        }
      } else {
#pragma unroll
        for (int j = 0; j < 4; ++j)
          oparts[(size_t)(r0 + j) * HH + n] = acc[mf][nf][j];
      }
    }
  }
}

// reduce for K-split GEMM2: out = x + gate*(p0 + p1 + 2*b2)
__global__ __launch_bounds__(256) void k_reduce(
    const float* __restrict__ parts, const float* __restrict__ x,
    const float* __restrict__ b2, const float* __restrict__ mod,
    float* __restrict__ out) {
  int gid = blockIdx.x * 256 + threadIdx.x;
  int r = gid / 768, c = (gid % 768) * 4;
  size_t idx = (size_t)r * HH + c;
  float4 a = *(const float4*)(parts + idx);
  float4 b = *(const float4*)(parts + (size_t)2048 * HH + idx);
  float4 xv = *(const float4*)(x + idx);
  float4 bb = *(const float4*)(b2 + c);
  float4 g = *(const float4*)(mod + 2 * HH + c);
  float4 o;
  o.x = xv.x + g.x * (a.x + b.x + 2.f * bb.x);
  o.y = xv.y + g.y * (a.y + b.y + 2.f * bb.y);
  o.z = xv.z + g.z * (a.z + b.z + 2.f * bb.z);
  o.w = xv.w + g.w * (a.w + b.w + 2.f * bb.w);
  *(float4*)(out + idx) = o;
}

// ---------------- RMSNorm + RoPE for q,k ----------------

__global__ __launch_bounds__(256) void k_rmsrope(
    const u16* __restrict__ qkv, const float* __restrict__ pe,
    const float* __restrict__ qs, const float* __restrict__ ks,
    u16* __restrict__ q_r, u16* __restrict__ k_r) {
  int gw = (blockIdx.x * 256 + threadIdx.x) >> 6;
  int lane = threadIdx.x & 63;
  int l = gw / NHEAD, h = gw % NHEAD;
  const u16* qp = qkv + (size_t)l * QKVW + h * HD;
  const u16* kp = qp + HH;
  ushort2 qu = *(const ushort2*)(qp + 2 * lane);
  ushort2 ku = *(const ushort2*)(kp + 2 * lane);
  float q0 = b2f(qu.x), q1 = b2f(qu.y);
  float k0 = b2f(ku.x), k1 = b2f(ku.y);
  float sq = q0 * q0 + q1 * q1, sk = k0 * k0 + k1 * k1;
#pragma unroll
  for (int m = 32; m; m >>= 1) { sq += __shfl_xor(sq, m); sk += __shfl_xor(sk, m); }
  float rq = rsqrtf(sq * (1.f / HD) + 1e-6f);
  float rk = rsqrtf(sk * (1.f / HD) + 1e-6f);
  float2 qsv = *(const float2*)(qs + 2 * lane);
  float2 ksv = *(const float2*)(ks + 2 * lane);
  q0 = q0 * rq * qsv.x; q1 = q1 * rq * qsv.y;
  k0 = k0 * rk * ksv.x; k1 = k1 * rk * ksv.y;
  float4 p = *(const float4*)(pe + (size_t)l * 256 + lane * 4);
  float oq0 = p.x * q0 + p.y * q1, oq1 = p.z * q0 + p.w * q1;
  float ok0 = p.x * k0 + p.y * k1, ok1 = p.z * k0 + p.w * k1;
  size_t o = ((size_t)h * LL + l) * HD + 2 * lane;
  ushort2 wq; wq.x = f2b(oq0); wq.y = f2b(oq1);
  ushort2 wk; wk.x = f2b(ok0); wk.y = f2b(ok1);
  *(ushort2*)(q_r + o) = wq;
  *(ushort2*)(k_r + o) = wk;
}

// ---------------- V transpose: qkv -> v_t [NH][D][L] ----------------

__global__ __launch_bounds__(256) void k_vtrans(const u16* __restrict__ qkv, u16* __restrict__ v_t) {
  __shared__ __align__(16) u16 tile[64][136];
  int h = blockIdx.y, l0 = blockIdx.x * 64, t = threadIdx.x;
#pragma unroll
  for (int i = 0; i < 4; i++) {
    int r = t >> 2, c = (t & 3) * 8 + i * 32;
    bf16x8 v = *(const bf16x8*)(qkv + (size_t)(l0 + r) * QKVW + 2 * HH + h * HD + c);
    *(bf16x8*)(&tile[r][c]) = v;
  }
  __syncthreads();
#pragma unroll
  for (int i = 0; i < 4; i++) {
    int d = t >> 1, lc = (t & 1) * 32 + i * 8;
    bf16x8 v;
#pragma unroll
    for (int j = 0; j < 8; j++) v[j] = (short)tile[lc + j][d];
    *(bf16x8*)(v_t + ((size_t)h * HD + d) * LL + l0 + lc) = v;
  }
}

// ---------------- Flash attention (swapped-QK^T, in-register softmax) ----------------
// q_r,k_r: [NH][L][D]; v_t: [NH][D][L]; writes h2[:, 0:3072]
// Per wave: 16 q-rows, KVBLK=64. mfma(K,Q) -> lane holds P[k=(lane>>4)*4+r+16si][q=lane&15]
// => row stats (max/sum over 64 k) = in-lane tree + 2 shfl_xor (masks 16,32).
// P staged through per-wave LDS row (XOR-swizzled elem^=(fr&7)<<3 on write AND read)
// to form the PV A-fragments. Defer-max (T13, THR=8) skips O-rescale when possible.

__global__ __launch_bounds__(256) void k_attn(
    const u16* __restrict__ q_r, const u16* __restrict__ k_r,
    const u16* __restrict__ v_t, u16* __restrict__ h2) {
  __shared__ __align__(16) u16 p_lds[4][16 * 72];   // row stride 72 elems = 144 B
  const int bid = xcd_swz(blockIdx.x, gridDim.x);
  const int h = bid >> 5;
  const int q0 = (bid & 31) * 64;
  const int t = threadIdx.x, lane = t & 63, w = t >> 6;
  const int fr = lane & 15, g = lane >> 4;
  const int msk = (fr & 7) << 3;                    // row-dependent XOR swizzle (elem units)
  // Q as B-operand: lane holds Q[q = q0+w*16+fr][d = kk*32 + g*8 + j]
  const u16* qbase = q_r + ((size_t)h * LL + q0 + w * 16 + fr) * HD + g * 8;
  bf16x8 aq[4];
#pragma unroll
  for (int kk = 0; kk < 4; kk++) aq[kk] = *(const bf16x8*)(qbase + kk * 32);
  float m_s = -1e30f, l_s = 0.f;                    // row stats for q = fr (replicated over g)
  f32x4 acc_o[8] = {};                              // O[q = g*4+r][d = d0*16+fr]
  const u16* kbase = k_r + ((size_t)h * LL + fr) * HD + g * 8;
  const u16* vbase = v_t + ((size_t)h * HD + fr) * LL + g * 8;
  u16* prow = &p_lds[w][0] + fr * 72;
  const float sc = 0.08838834764831845f;
  for (int kt = 0; kt < LL; kt += 64) {
    // --- QK^T, swapped: s[si] = K[kt+si*16 ..][*] x Q -> rows k, cols q
    f32x4 s[4] = {};
#pragma unroll
    for (int si = 0; si < 4; si++) {
      const u16* kp = kbase + (size_t)(kt + si * 16) * HD;
#pragma unroll
      for (int kk = 0; kk < 4; kk++) {
        bf16x8 kf = *(const bf16x8*)(kp + kk * 32);
        s[si] = __builtin_amdgcn_mfma_f32_16x16x32_bf16(kf, aq[kk], s[si], 0, 0, 0);
      }
    }
    // --- in-lane max over 16 k-values, then 2 shfls across g-groups
    float mx = s[0][0];
#pragma unroll
    for (int si = 0; si < 4; si++) {
      mx = fmaxf(mx, fmaxf(fmaxf(s[si][0], s[si][1]), fmaxf(s[si][2], s[si][3])));
    }
    mx = fmaxf(mx, __shfl_xor(mx, 16));
    mx = fmaxf(mx, __shfl_xor(mx, 32));
    float pmax = mx * sc;
    float mn = m_s;
    if (!__all(pmax - m_s <= 8.f)) {                // defer-max: rescale only on real growth
      mn = fmaxf(m_s, pmax);
      float al = __expf(m_s - mn);
      m_s = mn;
      l_s *= al;
      float alr[4];
#pragma unroll
      for (int r = 0; r < 4; r++) alr[r] = __shfl(al, g * 4 + r);
#pragma unroll
      for (int d0 = 0; d0 < 8; d0++) {
        acc_o[d0][0] *= alr[0]; acc_o[d0][1] *= alr[1];
        acc_o[d0][2] *= alr[2]; acc_o[d0][3] *= alr[3];
      }
    }
    // --- exp + pack to bf16 pairs + swizzled LDS store; in-lane sum + 2 shfls
    float tsum = 0.f;
#pragma unroll
    for (int si = 0; si < 4; si++) {
      float p0 = __expf(s[si][0] * sc - mn);
      float p1 = __expf(s[si][1] * sc - mn);
      float p2 = __expf(s[si][2] * sc - mn);
      float p3 = __expf(s[si][3] * sc - mn);
      tsum += (p0 + p1) + (p2 + p3);
      uint32_t w0 = (uint32_t)f2b(p0) | ((uint32_t)f2b(p1) << 16);
      uint32_t w1 = (uint32_t)f2b(p2) | ((uint32_t)f2b(p3) << 16);
      int c0 = (4 * g + 16 * si) ^ msk;             // even; msk bits >= 3
      *(uint32_t*)(prow + c0) = w0;
      *(uint32_t*)(prow + (c0 ^ 2)) = w1;
    }
    tsum += __shfl_xor(tsum, 16);
    tsum += __shfl_xor(tsum, 32);
    l_s += tsum;
    // --- PV: A-frags P[q=fr][k = kt + g*8+j (+32)], B = V_t rows (d), cols k
    bf16x8 pa0 = *(const bf16x8*)(prow + ((8 * g) ^ msk));
    bf16x8 pa1 = *(const bf16x8*)(prow + ((8 * g + 32) ^ msk));
#pragma unroll
    for (int d0 = 0; d0 < 8; d0++) {
      const u16* vp = vbase + (size_t)(d0 * 16) * LL + kt;
      bf16x8 bv0 = *(const bf16x8*)(vp);
      bf16x8 bv1 = *(const bf16x8*)(vp + 32);
      acc_o[d0] = __builtin_amdgcn_mfma_f32_16x16x32_bf16(pa0, bv0, acc_o[d0], 0, 0, 0);
      acc_o[d0] = __builtin_amdgcn_mfma_f32_16x16x32_bf16(pa1, bv1, acc_o[d0], 0, 0, 0);
    }
  }
  float linv[4];
#pragma unroll
  for (int r = 0; r < 4; r++) linv[r] = 1.f / __shfl(l_s, g * 4 + r);
#pragma unroll
  for (int r = 0; r < 4; r++) {
    int m = q0 + w * 16 + g * 4 + r;
#pragma unroll
    for (int d0 = 0; d0 < 8; d0++)
      h2[(size_t)m * K2 + h * HD + d0 * 16 + fr] = f2b(acc_o[d0][r] * linv[r]);
  }
}

// ---------------- launch ----------------

extern "C" void kernel_launch(void* const* d_in, const int* in_sizes, int n_in,
                              void* d_out, int out_size, void* d_ws, size_t ws_size,
                              hipStream_t stream) {
  const float* x = (const float*)d_in[0];
  const float* vec = (const float*)d_in[1];
  const float* pe = (const float*)d_in[2];
  const float* mod_w = (const float*)d_in[3];
  const float* mod_b = (const float*)d_in[4];
  const float* w1 = (const float*)d_in[5];
  const float* b1 = (const float*)d_in[6];
  const float* w2 = (const float*)d_in[7];
  const float* b2 = (const float*)d_in[8];
  const float* qs = (const float*)d_in[9];
  const float* ks = (const float*)d_in[10];
  float* out = (float*)d_out;

  char* ws = (char*)d_ws;
  float* sv    = (float*)(ws + 0);
  float* mod   = (float*)(ws + 12288);
  u16* xmod    = (u16*)(ws + 49152);
  u16* w1b     = (u16*)(ws + 12632064ULL);
  float* parts = (float*)(ws + 12632064ULL);   // aliases w1b (dead after GEMM1): 2x 25.2MB
  u16* w2b     = (u16*)(ws + 144752640ULL);
  u16* qkv     = (u16*)(ws + 239124480ULL);
  u16* q_r     = (u16*)(ws + 276873216ULL);
  u16* k_r     = (u16*)(ws + 289456128ULL);
  u16* v_t     = (u16*)(ws + 302039040ULL);
  u16* h2      = (u16*)(ws + 314621952ULL);

  k_silu<<<12, 256, 0, stream>>>(vec, sv, HH);
  k_f2b8<<<32256, 256, 0, stream>>>(w1, w1b, (size_t)N1 * HH);
  k_f2b8<<<23040, 256, 0, stream>>>(w2, w2b, (size_t)HH * K2);
  k_modlin<<<2304, 256, 0, stream>>>(sv, mod_w, mod_b, mod);
  k_ln<<<2048, 256, 0, stream>>>(x, mod, xmod);
  k_gemm256<0><<<672, 512, 0, stream>>>(xmod, w1b, b1, qkv, h2, nullptr);
  k_rmsrope<<<12288, 256, 0, stream>>>(qkv, pe, qs, ks, q_r, k_r);
  k_vtrans<<<dim3(32, 24), 256, 0, stream>>>(qkv, v_t);
  k_attn<<<768, 256, 0, stream>>>(q_r, k_r, v_t, h2);
  k_gemm256<1><<<192, 512, 0, stream>>>(h2, w2b, nullptr, nullptr, nullptr, parts);
  k_reduce<<<6144, 256, 0, stream>>>(parts, x, b2, mod, out);
}

// Round 6
// 772.395 us; speedup vs baseline: 1.3007x; 1.3007x over previous
//
#include <hip/hip_runtime.h>
#include <hip/hip_bf16.h>
#include <cstdint>
#include <cstddef>

typedef unsigned short u16;
typedef short bf16x8 __attribute__((ext_vector_type(8)));
typedef float f32x4 __attribute__((ext_vector_type(4)));

#define HH 3072
#define LL 2048
#define NHEAD 24
#define HD 128
#define MLP 12288
#define N1 21504   // 3H + M
#define QKVW 9216  // 3H
#define K2 15360   // H + M

__device__ __forceinline__ float b2f(u16 u) {
  union { float f; uint32_t i; } v; v.i = ((uint32_t)u) << 16; return v.f;
}
__device__ __forceinline__ u16 f2b(float f) {
  union { float f; uint32_t i; } v; v.f = f;
  return (u16)((v.i + 0x7fffu + ((v.i >> 16) & 1u)) >> 16);
}
__device__ __forceinline__ void gload16(const u16* g, u16* l) {
  __builtin_amdgcn_global_load_lds(
      (const __attribute__((address_space(1))) void*)g,
      (__attribute__((address_space(3))) void*)l, 16, 0, 0);
}
// bijective XCD-chunked swizzle (m204)
__device__ __forceinline__ int xcd_swz(int bid, int nwg) {
  int q = nwg >> 3, r = nwg & 7;
  int xcd = bid & 7, idx = bid >> 3;
  int base = (xcd < r) ? xcd * (q + 1) : r * (q + 1) + (xcd - r) * q;
  return base + idx;
}

// ---------------- small prep kernels ----------------

__global__ void k_silu(const float* __restrict__ vec, float* __restrict__ sv, int n) {
  int i = blockIdx.x * blockDim.x + threadIdx.x;
  if (i < n) { float v = vec[i]; sv[i] = v / (1.f + expf(-v)); }
}

__global__ void k_f2b8(const float* __restrict__ in, u16* __restrict__ out, size_t n) {
  size_t i = ((size_t)blockIdx.x * blockDim.x + threadIdx.x) * 8;
  if (i >= n) return;
  float4 a = *(const float4*)(in + i);
  float4 b = *(const float4*)(in + i + 4);
  bf16x8 o;
  o[0] = (short)f2b(a.x); o[1] = (short)f2b(a.y); o[2] = (short)f2b(a.z); o[3] = (short)f2b(a.w);
  o[4] = (short)f2b(b.x); o[5] = (short)f2b(b.y); o[6] = (short)f2b(b.z); o[7] = (short)f2b(b.w);
  *(bf16x8*)(out + i) = o;
}

__global__ __launch_bounds__(256) void k_modlin(
    const float* __restrict__ sv, const float* __restrict__ mw,
    const float* __restrict__ mb, float* __restrict__ mod) {
  int wave = (blockIdx.x * 256 + threadIdx.x) >> 6;
  int lane = threadIdx.x & 63;
  if (wave >= QKVW) return;
  const float* row = mw + (size_t)wave * HH;
  float s = 0.f;
#pragma unroll
  for (int i = 0; i < 12; i++) {
    int idx = i * 256 + lane * 4;
    float4 a = *(const float4*)(row + idx);
    float4 b = *(const float4*)(sv + idx);
    s += a.x * b.x + a.y * b.y + a.z * b.z + a.w * b.w;
  }
#pragma unroll
  for (int m = 32; m; m >>= 1) s += __shfl_xor(s, m);
  if (lane == 0) mod[wave] = s + mb[wave];
}

__global__ __launch_bounds__(256) void k_ln(
    const float* __restrict__ x, const float* __restrict__ mod, u16* __restrict__ xmod) {
  int row = blockIdx.x, t = threadIdx.x, lane = t & 63, w = t >> 6;
  const float* xr = x + (size_t)row * HH;
  float4 v[3];
  float s1 = 0.f, s2 = 0.f;
#pragma unroll
  for (int i = 0; i < 3; i++) {
    v[i] = *(const float4*)(xr + t * 4 + i * 1024);
    s1 += v[i].x + v[i].y + v[i].z + v[i].w;
    s2 += v[i].x * v[i].x + v[i].y * v[i].y + v[i].z * v[i].z + v[i].w * v[i].w;
  }
#pragma unroll
  for (int m = 32; m; m >>= 1) { s1 += __shfl_xor(s1, m); s2 += __shfl_xor(s2, m); }
  __shared__ float red[8];
  if (lane == 0) { red[w] = s1; red[4 + w] = s2; }
  __syncthreads();
  s1 = red[0] + red[1] + red[2] + red[3];
  s2 = red[4] + red[5] + red[6] + red[7];
  float mu = s1 * (1.f / HH);
  float var = s2 * (1.f / HH) - mu * mu;
  float rstd = rsqrtf(var + 1e-6f);
#pragma unroll
  for (int i = 0; i < 3; i++) {
    int nb = t * 4 + i * 1024;
    ushort4 o;
    o.x = f2b((v[i].x - mu) * rstd * (1.f + mod[HH + nb + 0]) + mod[nb + 0]);
    o.y = f2b((v[i].y - mu) * rstd * (1.f + mod[HH + nb + 1]) + mod[nb + 1]);
    o.z = f2b((v[i].z - mu) * rstd * (1.f + mod[HH + nb + 2]) + mod[nb + 2]);
    o.w = f2b((v[i].w - mu) * rstd * (1.f + mod[HH + nb + 3]) + mod[nb + 3]);
    *(ushort4*)(xmod + (size_t)row * HH + nb) = o;
  }
}

// ================= 256x256 8-phase GEMM (m201 template, plain HIP) =================
// (unchanged — verified passing)

#define MFMA_Q(AF, MB) do {                                                                   \
  _Pragma("unroll")                                                                           \
  for (int nf_ = 0; nf_ < 4; ++nf_) {                                                         \
    acc[MB][nf_]     = __builtin_amdgcn_mfma_f32_16x16x32_bf16(AF[0][0], bfr[nf_][0], acc[MB][nf_],     0,0,0); \
    acc[MB][nf_]     = __builtin_amdgcn_mfma_f32_16x16x32_bf16(AF[0][1], bfr[nf_][1], acc[MB][nf_],     0,0,0); \
    acc[(MB)+1][nf_] = __builtin_amdgcn_mfma_f32_16x16x32_bf16(AF[1][0], bfr[nf_][0], acc[(MB)+1][nf_], 0,0,0); \
    acc[(MB)+1][nf_] = __builtin_amdgcn_mfma_f32_16x16x32_bf16(AF[1][1], bfr[nf_][1], acc[(MB)+1][nf_], 0,0,0); \
  } } while (0)

#define STA(tt, half) do {                                                                    \
  const u16* g_ = gA + (size_t)((half) * 128) * kstride + (size_t)(tt) * 64;                  \
  int l_ = lA + ((tt) & 1) * 16384 + (half) * 8192;                                           \
  gload16(g_, lds + l_); gload16(g_ + 64 * kstride, lds + l_ + 4096); } while (0)

#define STB(tt, half) do {                                                                    \
  const u16* g_ = gB + (size_t)((half) * 128) * kstride + (size_t)(tt) * 64;                  \
  int l_ = lB + ((tt) & 1) * 16384 + (half) * 8192;                                           \
  gload16(g_, lds + l_); gload16(g_ + 64 * kstride, lds + l_ + 4096); } while (0)

template <int MODE>
__global__ __launch_bounds__(512, 2) void k_gemm256(
    const u16* __restrict__ Aall, const u16* __restrict__ Ball,
    const float* __restrict__ bias, u16* __restrict__ oq,
    u16* __restrict__ oh2, float* __restrict__ oparts) {
  __shared__ __align__(16) u16 lds[65536];   // 131072 bytes: A [0,32768), B [32768,65536)
  const int wgid = xcd_swz(blockIdx.x, gridDim.x);
  int m0, n0, NT; size_t kstride;
  const u16 *A, *Bw;
  if (MODE == 0) {
    m0 = (wgid & 7) * 256; n0 = (wgid >> 3) * 256; NT = 48; kstride = 3072;
    A = Aall + (size_t)m0 * kstride; Bw = Ball + (size_t)n0 * kstride;
  } else {
    m0 = (wgid & 7) * 256; int ks = (wgid >> 3) & 1; n0 = (wgid >> 4) * 256; NT = 120; kstride = 15360;
    A = Aall + (size_t)m0 * kstride + (size_t)ks * 7680;
    Bw = Ball + (size_t)n0 * kstride + (size_t)ks * 7680;
    oparts += (size_t)ks * 2048 * 3072;
  }
  const int tid = threadIdx.x, lane = tid & 63, w = tid >> 6;
  const int wr = w >> 2, wc = w & 3;
  const int fr = lane & 15, gq = lane >> 4;
  const int apb = ((gq ^ (fr & 3)) | (fr & 4)) * 8;
  const int aoff = wr * 8192 + fr * 64 + apb;
  const int boff = 32768 + (wc >> 1) * 8192 + ((wc & 1) * 64 + fr) * 64 + apb;
  const int srow = w * 8 + (lane >> 3);
  const int scol = ((lane & 7) ^ (lane >> 3)) * 8;
  const u16* gA = A + (size_t)srow * kstride + scol;
  const u16* gB = Bw + (size_t)srow * kstride + scol;
  const int lA = w * 512 + lane * 8;
  const int lB = 32768 + w * 512 + lane * 8;

  f32x4 acc[8][4] = {};
  STB(0, 0); STB(0, 1); STA(0, 0); STA(0, 1);
  STB(1, 0); STB(1, 1); STA(1, 0);
  asm volatile("s_waitcnt vmcnt(6)" ::: "memory");
  __builtin_amdgcn_s_barrier();

  for (int t = 0; t < NT; ++t) {
    const int p16 = (t & 1) * 16384;
    bf16x8 bfr[4][2], aA[2][2], aB[2][2], aC[2][2], aD[2][2];
#pragma unroll
    for (int nf = 0; nf < 4; ++nf) {
      int ix = boff + p16 + nf * 1024;
      bfr[nf][0] = *(const bf16x8*)(lds + ix);
      bfr[nf][1] = *(const bf16x8*)(lds + (ix ^ 32));
    }
#pragma unroll
    for (int mf = 0; mf < 2; ++mf) {
      int ix = aoff + p16 + mf * 1024;
      aA[mf][0] = *(const bf16x8*)(lds + ix);
      aA[mf][1] = *(const bf16x8*)(lds + (ix ^ 32));
    }
    if (t + 1 < NT) STA(t + 1, 1);
    __builtin_amdgcn_s_barrier();
    asm volatile("s_waitcnt lgkmcnt(0)" ::: "memory");
    __builtin_amdgcn_s_setprio(1);
    MFMA_Q(aA, 0);
    __builtin_amdgcn_s_setprio(0);
    __builtin_amdgcn_s_barrier();
#pragma unroll
    for (int mf = 0; mf < 2; ++mf) {
      int ix = aoff + p16 + (mf + 2) * 1024;
      aB[mf][0] = *(const bf16x8*)(lds + ix);
      aB[mf][1] = *(const bf16x8*)(lds + (ix ^ 32));
    }
#pragma unroll
    for (int mf = 0; mf < 2; ++mf) {
      int ix = aoff + p16 + (mf + 4) * 1024;
      aC[mf][0] = *(const bf16x8*)(lds + ix);
      aC[mf][1] = *(const bf16x8*)(lds + (ix ^ 32));
    }
    if (t + 2 < NT) STB(t + 2, 0);
    __builtin_amdgcn_s_barrier();
    asm volatile("s_waitcnt lgkmcnt(0)" ::: "memory");
    __builtin_amdgcn_s_setprio(1);
    MFMA_Q(aB, 2);
    __builtin_amdgcn_s_setprio(0);
    __builtin_amdgcn_s_barrier();
#pragma unroll
    for (int mf = 0; mf < 2; ++mf) {
      int ix = aoff + p16 + (mf + 6) * 1024;
      aD[mf][0] = *(const bf16x8*)(lds + ix);
      aD[mf][1] = *(const bf16x8*)(lds + (ix ^ 32));
    }
    if (t + 2 < NT) STB(t + 2, 1);
    __builtin_amdgcn_s_barrier();
    asm volatile("s_waitcnt lgkmcnt(0)" ::: "memory");
    __builtin_amdgcn_s_setprio(1);
    MFMA_Q(aC, 4);
    __builtin_amdgcn_s_setprio(0);
    __builtin_amdgcn_s_barrier();
    if (t + 2 < NT) STA(t + 2, 0);
    __builtin_amdgcn_s_barrier();
    __builtin_amdgcn_s_setprio(1);
    MFMA_Q(aD, 6);
    __builtin_amdgcn_s_setprio(0);
    if (t + 2 < NT)      asm volatile("s_waitcnt vmcnt(6)" ::: "memory");
    else if (t + 1 < NT) asm volatile("s_waitcnt vmcnt(0)" ::: "memory");
    __builtin_amdgcn_s_barrier();
  }

#pragma unroll
  for (int mf = 0; mf < 8; ++mf) {
    const int r0 = m0 + wr * 128 + mf * 16 + gq * 4;
#pragma unroll
    for (int nf = 0; nf < 4; ++nf) {
      const int n = n0 + wc * 64 + nf * 16 + fr;
      if (MODE == 0) {
        const float bv = bias[n];
        if (n0 >= QKVW) {
#pragma unroll
          for (int j = 0; j < 4; ++j) {
            float u = acc[mf][nf][j] + bv;
            float c = 0.7978845608028654f * (u + 0.044715f * u * u * u);
            float g = 0.5f * u * (1.f + tanhf(c));
            oh2[(size_t)(r0 + j) * K2 + HH + (n - QKVW)] = f2b(g);
          }
        } else {
#pragma unroll
          for (int j = 0; j < 4; ++j)
            oq[(size_t)(r0 + j) * QKVW + n] = f2b(acc[mf][nf][j] + bv);
        }
      } else {
#pragma unroll
        for (int j = 0; j < 4; ++j)
          oparts[(size_t)(r0 + j) * HH + n] = acc[mf][nf][j];
      }
    }
  }
}

// reduce for K-split GEMM2: out = x + gate*(p0 + p1 + 2*b2)
__global__ __launch_bounds__(256) void k_reduce(
    const float* __restrict__ parts, const float* __restrict__ x,
    const float* __restrict__ b2, const float* __restrict__ mod,
    float* __restrict__ out) {
  int gid = blockIdx.x * 256 + threadIdx.x;
  int r = gid / 768, c = (gid % 768) * 4;
  size_t idx = (size_t)r * HH + c;
  float4 a = *(const float4*)(parts + idx);
  float4 b = *(const float4*)(parts + (size_t)2048 * HH + idx);
  float4 xv = *(const float4*)(x + idx);
  float4 bb = *(const float4*)(b2 + c);
  float4 g = *(const float4*)(mod + 2 * HH + c);
  float4 o;
  o.x = xv.x + g.x * (a.x + b.x + 2.f * bb.x);
  o.y = xv.y + g.y * (a.y + b.y + 2.f * bb.y);
  o.z = xv.z + g.z * (a.z + b.z + 2.f * bb.z);
  o.w = xv.w + g.w * (a.w + b.w + 2.f * bb.w);
  *(float4*)(out + idx) = o;
}

// ---------------- RMSNorm + RoPE for q,k ----------------

__global__ __launch_bounds__(256) void k_rmsrope(
    const u16* __restrict__ qkv, const float* __restrict__ pe,
    const float* __restrict__ qs, const float* __restrict__ ks,
    u16* __restrict__ q_r, u16* __restrict__ k_r) {
  int gw = (blockIdx.x * 256 + threadIdx.x) >> 6;
  int lane = threadIdx.x & 63;
  int l = gw / NHEAD, h = gw % NHEAD;
  const u16* qp = qkv + (size_t)l * QKVW + h * HD;
  const u16* kp = qp + HH;
  ushort2 qu = *(const ushort2*)(qp + 2 * lane);
  ushort2 ku = *(const ushort2*)(kp + 2 * lane);
  float q0 = b2f(qu.x), q1 = b2f(qu.y);
  float k0 = b2f(ku.x), k1 = b2f(ku.y);
  float sq = q0 * q0 + q1 * q1, sk = k0 * k0 + k1 * k1;
#pragma unroll
  for (int m = 32; m; m >>= 1) { sq += __shfl_xor(sq, m); sk += __shfl_xor(sk, m); }
  float rq = rsqrtf(sq * (1.f / HD) + 1e-6f);
  float rk = rsqrtf(sk * (1.f / HD) + 1e-6f);
  float2 qsv = *(const float2*)(qs + 2 * lane);
  float2 ksv = *(const float2*)(ks + 2 * lane);
  q0 = q0 * rq * qsv.x; q1 = q1 * rq * qsv.y;
  k0 = k0 * rk * ksv.x; k1 = k1 * rk * ksv.y;
  float4 p = *(const float4*)(pe + (size_t)l * 256 + lane * 4);
  float oq0 = p.x * q0 + p.y * q1, oq1 = p.z * q0 + p.w * q1;
  float ok0 = p.x * k0 + p.y * k1, ok1 = p.z * k0 + p.w * k1;
  size_t o = ((size_t)h * LL + l) * HD + 2 * lane;
  ushort2 wq; wq.x = f2b(oq0); wq.y = f2b(oq1);
  ushort2 wk; wk.x = f2b(ok0); wk.y = f2b(ok1);
  *(ushort2*)(q_r + o) = wq;
  *(ushort2*)(k_r + o) = wk;
}

// ---------------- V transpose: qkv -> v_t [NH][D][L] ----------------

__global__ __launch_bounds__(256) void k_vtrans(const u16* __restrict__ qkv, u16* __restrict__ v_t) {
  __shared__ __align__(16) u16 tile[64][136];
  int h = blockIdx.y, l0 = blockIdx.x * 64, t = threadIdx.x;
#pragma unroll
  for (int i = 0; i < 4; i++) {
    int r = t >> 2, c = (t & 3) * 8 + i * 32;
    bf16x8 v = *(const bf16x8*)(qkv + (size_t)(l0 + r) * QKVW + 2 * HH + h * HD + c);
    *(bf16x8*)(&tile[r][c]) = v;
  }
  __syncthreads();
#pragma unroll
  for (int i = 0; i < 4; i++) {
    int d = t >> 1, lc = (t & 1) * 32 + i * 8;
    bf16x8 v;
#pragma unroll
    for (int j = 0; j < 8; j++) v[j] = (short)tile[lc + j][d];
    *(bf16x8*)(v_t + ((size_t)h * HD + d) * LL + l0 + lc) = v;
  }
}

// ---------------- Flash attention (LDS-staged K/V + swapped-QK^T softmax) ----------------
// q_r,k_r: [NH][L][D]; v_t: [NH][D][L]; writes h2[:, 0:3072]
// K tile [64 k][128 d], V tile [128 d][64 k] staged in LDS via global_load_lds,
// 16B-block XOR swizzle (phys blk = logical blk ^ (row&7)) applied on SOURCE + READ
// (rule 21: both-sides-or-neither). Single buffer, m97-style sync; the 3 co-resident
// blocks/CU provide the implicit overlap (m114). Softmax path unchanged from round 5.

__global__ __launch_bounds__(256) void k_attn(
    const u16* __restrict__ q_r, const u16* __restrict__ k_r,
    const u16* __restrict__ v_t, u16* __restrict__ h2) {
  __shared__ __align__(16) u16 kbuf[64 * 128];     // 16 KB
  __shared__ __align__(16) u16 vbuf[128 * 64];     // 16 KB
  __shared__ __align__(16) u16 p_lds[4][16 * 72];  // 9 KB
  const int bid = xcd_swz(blockIdx.x, gridDim.x);
  const int h = bid >> 5;
  const int q0 = (bid & 31) * 64;
  const int t = threadIdx.x, lane = t & 63, w = t >> 6;
  const int fr = lane & 15, g = lane >> 4;
  const int msk = (fr & 7) << 3;                   // P-buffer swizzle (elem units)
  const int fsw = fr & 7;                          // K/V LDS block swizzle key
  // Q fragments (global, once per block)
  const u16* qbase = q_r + ((size_t)h * LL + q0 + w * 16 + fr) * HD + g * 8;
  bf16x8 aq[4];
#pragma unroll
  for (int kk = 0; kk < 4; kk++) aq[kk] = *(const bf16x8*)(qbase + kk * 32);
  // staging addresses (pre-swizzled global source, linear LDS dest)
  const int krow = t >> 4, kblk = t & 15;
  const u16* kg = k_r + ((size_t)h * LL + krow) * HD + (kblk ^ (krow & 7)) * 8;
  const int vrow = t >> 3, vblk = t & 7;
  const u16* vg = v_t + ((size_t)h * HD + vrow) * LL + (vblk ^ (vrow & 7)) * 8;
  u16* kl = kbuf + t * 8;
  u16* vl = vbuf + t * 8;

  float m_s = -1e30f, l_s = 0.f;
  f32x4 acc_o[8] = {};
  u16* prow = &p_lds[w][0] + fr * 72;
  const float sc = 0.08838834764831845f;

  for (int kt = 0; kt < LL; kt += 64) {
    if (kt) __syncthreads();                       // prev tile's LDS reads done
#pragma unroll
    for (int p = 0; p < 4; p++)
      gload16(kg + (size_t)(kt + p * 16) * HD, kl + p * 2048);
#pragma unroll
    for (int p = 0; p < 4; p++)
      gload16(vg + (size_t)(p * 32) * LL + kt, vl + p * 2048);
    asm volatile("s_waitcnt vmcnt(0)" ::: "memory");
    __syncthreads();                               // tile resident for all waves
    // --- QK^T (swapped): s[si] = K x Q -> rows k, cols q
    f32x4 s[4] = {};
#pragma unroll
    for (int si = 0; si < 4; si++) {
#pragma unroll
      for (int kk = 0; kk < 4; kk++) {
        bf16x8 kf = *(const bf16x8*)(kbuf + (si * 16 + fr) * 128 + ((4 * kk + g) ^ fsw) * 8);
        s[si] = __builtin_amdgcn_mfma_f32_16x16x32_bf16(kf, aq[kk], s[si], 0, 0, 0);
      }
    }
    // --- in-lane max over 16 k-values, then 2 shfls across g-groups
    float mx = s[0][0];
#pragma unroll
    for (int si = 0; si < 4; si++)
      mx = fmaxf(mx, fmaxf(fmaxf(s[si][0], s[si][1]), fmaxf(s[si][2], s[si][3])));
    mx = fmaxf(mx, __shfl_xor(mx, 16));
    mx = fmaxf(mx, __shfl_xor(mx, 32));
    float pmax = mx * sc;
    float mn = m_s;
    if (!__all(pmax - m_s <= 8.f)) {               // defer-max (T13)
      mn = fmaxf(m_s, pmax);
      float al = __expf(m_s - mn);
      m_s = mn;
      l_s *= al;
      float alr[4];
#pragma unroll
      for (int r = 0; r < 4; r++) alr[r] = __shfl(al, g * 4 + r);
#pragma unroll
      for (int d0 = 0; d0 < 8; d0++) {
        acc_o[d0][0] *= alr[0]; acc_o[d0][1] *= alr[1];
        acc_o[d0][2] *= alr[2]; acc_o[d0][3] *= alr[3];
      }
    }
    // --- exp + pack + swizzled P store; in-lane sum + 2 shfls
    float tsum = 0.f;
#pragma unroll
    for (int si = 0; si < 4; si++) {
      float p0 = __expf(s[si][0] * sc - mn);
      float p1 = __expf(s[si][1] * sc - mn);
      float p2 = __expf(s[si][2] * sc - mn);
      float p3 = __expf(s[si][3] * sc - mn);
      tsum += (p0 + p1) + (p2 + p3);
      uint32_t w0 = (uint32_t)f2b(p0) | ((uint32_t)f2b(p1) << 16);
      uint32_t w1 = (uint32_t)f2b(p2) | ((uint32_t)f2b(p3) << 16);
      int c0 = (4 * g + 16 * si) ^ msk;
      *(uint32_t*)(prow + c0) = w0;
      *(uint32_t*)(prow + (c0 ^ 2)) = w1;
    }
    tsum += __shfl_xor(tsum, 16);
    tsum += __shfl_xor(tsum, 32);
    l_s += tsum;
    // --- PV from LDS V tile (swizzled reads)
    bf16x8 pa0 = *(const bf16x8*)(prow + ((8 * g) ^ msk));
    bf16x8 pa1 = *(const bf16x8*)(prow + ((8 * g + 32) ^ msk));
#pragma unroll
    for (int d0 = 0; d0 < 8; d0++) {
      const u16* vrow_p = vbuf + (d0 * 16 + fr) * 64;
      bf16x8 bv0 = *(const bf16x8*)(vrow_p + ((g ^ fsw) * 8));
      bf16x8 bv1 = *(const bf16x8*)(vrow_p + (((g + 4) ^ fsw) * 8));
      acc_o[d0] = __builtin_amdgcn_mfma_f32_16x16x32_bf16(pa0, bv0, acc_o[d0], 0, 0, 0);
      acc_o[d0] = __builtin_amdgcn_mfma_f32_16x16x32_bf16(pa1, bv1, acc_o[d0], 0, 0, 0);
    }
  }
  float linv[4];
#pragma unroll
  for (int r = 0; r < 4; r++) linv[r] = 1.f / __shfl(l_s, g * 4 + r);
#pragma unroll
  for (int r = 0; r < 4; r++) {
    int m = q0 + w * 16 + g * 4 + r;
#pragma unroll
    for (int d0 = 0; d0 < 8; d0++)
      h2[(size_t)m * K2 + h * HD + d0 * 16 + fr] = f2b(acc_o[d0][r] * linv[r]);
  }
}

// ---------------- launch ----------------

extern "C" void kernel_launch(void* const* d_in, const int* in_sizes, int n_in,
                              void* d_out, int out_size, void* d_ws, size_t ws_size,
                              hipStream_t stream) {
  const float* x = (const float*)d_in[0];
  const float* vec = (const float*)d_in[1];
  const float* pe = (const float*)d_in[2];
  const float* mod_w = (const float*)d_in[3];
  const float* mod_b = (const float*)d_in[4];
  const float* w1 = (const float*)d_in[5];
  const float* b1 = (const float*)d_in[6];
  const float* w2 = (const float*)d_in[7];
  const float* b2 = (const float*)d_in[8];
  const float* qs = (const float*)d_in[9];
  const float* ks = (const float*)d_in[10];
  float* out = (float*)d_out;

  char* ws = (char*)d_ws;
  float* sv    = (float*)(ws + 0);
  float* mod   = (float*)(ws + 12288);
  u16* xmod    = (u16*)(ws + 49152);
  u16* w1b     = (u16*)(ws + 12632064ULL);
  float* parts = (float*)(ws + 12632064ULL);   // aliases w1b (dead after GEMM1): 2x 25.2MB
  u16* w2b     = (u16*)(ws + 144752640ULL);
  u16* qkv     = (u16*)(ws + 239124480ULL);
  u16* q_r     = (u16*)(ws + 276873216ULL);
  u16* k_r     = (u16*)(ws + 289456128ULL);
  u16* v_t     = (u16*)(ws + 302039040ULL);
  u16* h2      = (u16*)(ws + 314621952ULL);

  k_silu<<<12, 256, 0, stream>>>(vec, sv, HH);
  k_f2b8<<<32256, 256, 0, stream>>>(w1, w1b, (size_t)N1 * HH);
  k_f2b8<<<23040, 256, 0, stream>>>(w2, w2b, (size_t)HH * K2);
  k_modlin<<<2304, 256, 0, stream>>>(sv, mod_w, mod_b, mod);
  k_ln<<<2048, 256, 0, stream>>>(x, mod, xmod);
  k_gemm256<0><<<672, 512, 0, stream>>>(xmod, w1b, b1, qkv, h2, nullptr);
  k_rmsrope<<<12288, 256, 0, stream>>>(qkv, pe, qs, ks, q_r, k_r);
  k_vtrans<<<dim3(32, 24), 256, 0, stream>>>(qkv, v_t);
  k_attn<<<768, 256, 0, stream>>>(q_r, k_r, v_t, h2);
  k_gemm256<1><<<192, 512, 0, stream>>>(h2, w2b, nullptr, nullptr, nullptr, parts);
  k_reduce<<<6144, 256, 0, stream>>>(parts, x, b2, mod, out);
}